// Round 11
// baseline (112.362 us; speedup 1.0000x reference)
//
#include <hip/hip_runtime.h>
#include <hip/hip_bf16.h>

// CapsuleConv2d fused, MFMA edition v10 = v6 + rep x4 counter-surfacing probe.
// N=4, C=64 (G=8 x IN_LEN=8), H=W=32, O=8, L=16, F=72 (G x 3x3), pad1 stride1.
//
// PROBE: grid 8192 = 4 x 2048; b = blockIdx.x & 2047 -> each block repeated 4x
// (identical math, duplicate identical writes). Purpose: make caps_main's dur
// (~63us) exceed the 41us ws-poison fills so its PMC row (VALUBusy, MfmaUtil,
// VGPR_Count, SQ_LDS_BANK_CONFLICT, Occupancy) finally appears in top-5.
// Model under test: caps = 16us base + 11.8us per 2048 blocks -> dur ~= 99-103.
//
// Kernel body is bit-identical to v6 (best, 75.67us).

typedef short bf16x8 __attribute__((ext_vector_type(8)));
typedef float f32x4 __attribute__((ext_vector_type(4)));
typedef unsigned int uint2v __attribute__((ext_vector_type(2)));

__device__ __forceinline__ float red16(float v) {
#if __has_builtin(__builtin_amdgcn_permlane16_swap)
  uint2v r = __builtin_amdgcn_permlane16_swap(__float_as_uint(v), __float_as_uint(v),
                                              false, false);
  return __uint_as_float(r[0]) + __uint_as_float(r[1]);
#else
  return v + __shfl_xor(v, 16);
#endif
}

__device__ __forceinline__ float red32(float v) {
#if __has_builtin(__builtin_amdgcn_permlane32_swap)
  uint2v r = __builtin_amdgcn_permlane32_swap(__float_as_uint(v), __float_as_uint(v),
                                              false, false);
  return __uint_as_float(r[0]) + __uint_as_float(r[1]);
#else
  return v + __shfl_xor(v, 32);
#endif
}

__device__ __forceinline__ uint pack_split(float v) {
  __hip_bfloat16 hb = __float2bfloat16(v);
  float hf = __bfloat162float(hb);
  __hip_bfloat16 lb = __float2bfloat16(v - hf);
  return (uint)(*(ushort*)&hb) | ((uint)(*(ushort*)&lb) << 16);
}

__global__ __launch_bounds__(256)
void prep(const float* __restrict__ x, const float* __restrict__ w,
          ushort* __restrict__ wT, ushort* __restrict__ xT) {
  const int b = blockIdx.x;
  if (b < 128) {
    // ---- x part: one h-row (32 pixels) per block ----
    __shared__ uint lds[32 * 65];  // [pix][c], hi|lo packed
    const int n = b >> 5, h0 = b & 31;
    const float* src = x + n * 65536 + h0 * 32;
    for (int i = threadIdx.x; i < 2048; i += 256) {
      const int c = i >> 5, p = i & 31;
      lds[p * 65 + c] = pack_split(src[c * 1024 + p]);
    }
    __syncthreads();
    uint* dst = (uint*)xT + (n * 1024 + h0 * 32) * 64;
    for (int i = threadIdx.x; i < 512; i += 256) {
      const int pix = i >> 4, seg = i & 15;        // seg 0..7 hi, 8..15 lo
      const uint* row = &lds[pix * 65 + (seg & 7) * 8];
      uint4 v;
      if (seg < 8) {
        v.x = (row[0] & 0xffffu) | (row[1] << 16);
        v.y = (row[2] & 0xffffu) | (row[3] << 16);
        v.z = (row[4] & 0xffffu) | (row[5] << 16);
        v.w = (row[6] & 0xffffu) | (row[7] << 16);
      } else {
        v.x = (row[0] >> 16) | (row[1] & 0xffff0000u);
        v.y = (row[2] >> 16) | (row[3] & 0xffff0000u);
        v.z = (row[4] >> 16) | (row[5] & 0xffff0000u);
        v.w = (row[6] >> 16) | (row[7] & 0xffff0000u);
      }
      *(uint4*)(dst + pix * 64 + seg * 4) = v;
    }
  } else {
    // ---- w part: t = record index (o*72+f)*16+l, 9216 total ----
    const int t = (b - 128) * 256 + threadIdx.x;
    if (t >= 9216) return;
    const float* src = w + t * 8;
    uint hi[4], lo[4];
    #pragma unroll
    for (int p2 = 0; p2 < 4; ++p2) {
      uint a = pack_split(src[p2 * 2]);
      uint c = pack_split(src[p2 * 2 + 1]);
      hi[p2] = (a & 0xffffu) | (c << 16);
      lo[p2] = (a >> 16) | (c & 0xffff0000u);
    }
    uint* dstp = (uint*)(wT + t * 16);
    *(uint4*)dstp       = make_uint4(hi[0], hi[1], hi[2], hi[3]);
    *(uint4*)(dstp + 4) = make_uint4(lo[0], lo[1], lo[2], lo[3]);
  }
}

__global__ __launch_bounds__(256, 3)
void caps_main(const ushort* __restrict__ wT, const ushort* __restrict__ xT,
               float* __restrict__ out) {
  const int b  = blockIdx.x & 2047;      // rep = blockIdx.x >> 11 (probe x4)
  const int wt = b & 1, h = (b >> 1) & 31, o = (b >> 6) & 7, n = b >> 9;
  const int w0 = wt * 16;
  const int tid = threadIdx.x, lane = tid & 63, fq = tid >> 6;
  const int pix = lane & 15, q = lane >> 4;

  // x window: 3 rows x 18 cols, per col 64 uints ([hi 32 | lo 32]), stride 68
  __shared__ uint  xs[54 * 68];          // 14688 B
  __shared__ float sbuf[2][4 * 256];     // 8192 B, parity-buffered s exchange

  // ---- stage x window (uint4 copies; zero-fill pads) ----
  for (int i = tid; i < 54 * 16; i += 256) {
    const int r = i >> 4, seg = i & 15;
    const int kh = r / 18, c = r % 18;
    const int hh = h + kh - 1, ww = w0 + c - 1;
    uint4 v = make_uint4(0u, 0u, 0u, 0u);
    if ((unsigned)hh < 32u && (unsigned)ww < 32u) {
      const uint* g = (const uint*)xT + (n * 1024 + hh * 32 + ww) * 64 + seg * 4;
      v = *(const uint4*)g;
    }
    *(uint4*)&xs[r * 68 + seg * 4] = v;
  }
  __syncthreads();

  // ---- priors: 18 MFMAs, one per f = fq*18 + j; exact bf16-split ----
  f32x4 P[18];
  const f32x4 zacc = {0.f, 0.f, 0.f, 0.f};
  // A: lane m holds record (o, f, l=m); k-octet q reads hi (q<2) or lo (q>=2).
  const ushort* wA = wT + ((o * 72 + fq * 18) * 16 + pix) * 16 + ((q >= 2) ? 8 : 0);
  // B: k-octet q reads hi (q even) / lo (q odd) half of the x column.
  const int xw_lane = pix * 68 + ((q & 1) ? 32 : 0);
  #pragma unroll
  for (int j = 0; j < 18; ++j) {
    const int g = fq * 2 + (j >= 9 ? 1 : 0);
    const int s = j % 9, kh = s / 3, kw = s % 3;
    const bf16x8 a  = *(const bf16x8*)(wA + j * 256);
    const bf16x8 bv = *(const bf16x8*)&xs[(kh * 18 + kw) * 68 + g * 4 + xw_lane];
    P[j] = __builtin_amdgcn_mfma_f32_16x16x32_bf16(a, bv, zacc, 0, 0, 0);
  }

  // ---- routing: lane owns (pix, l = q*4 + reg), 18 f x 4 l priors in regs ----
  float c[18];
  #pragma unroll
  for (int j = 0; j < 18; ++j) c[j] = 1.f;

  // swizzled slot: 16 consecutive lanes cover all 8 four-bank windows (2-way).
  const int sidx = pix * 16 + (((q + (pix >> 1)) & 3) << 2);
  #pragma unroll
  for (int it = 0; it < 3; ++it) {
    f32x4 sp = {0.f, 0.f, 0.f, 0.f};
    #pragma unroll
    for (int j = 0; j < 18; ++j) {
      sp.x += c[j] * P[j].x; sp.y += c[j] * P[j].y;
      sp.z += c[j] * P[j].z; sp.w += c[j] * P[j].w;
    }
    float* sb = sbuf[it & 1];
    *(f32x4*)&sb[fq * 256 + sidx] = sp;
    __syncthreads();
    f32x4 sv = *(const f32x4*)&sb[sidx];
    #pragma unroll
    for (int k4 = 1; k4 < 4; ++k4) {
      f32x4 t = *(const f32x4*)&sb[k4 * 256 + sidx];
      sv.x += t.x; sv.y += t.y; sv.z += t.z; sv.w += t.w;
    }
    sv.x *= 0.125f; sv.y *= 0.125f; sv.z *= 0.125f; sv.w *= 0.125f;
    // squash: qq = sum_l s^2 (4 in-reg + VALU permlane over the 4 lq lanes)
    float qq = sv.x * sv.x + sv.y * sv.y + sv.z * sv.z + sv.w * sv.w;
    qq = red32(red16(qq));
    const float k = sqrtf(qq) / (1.f + qq);
    f32x4 ov;
    ov.x = sv.x * k; ov.y = sv.y * k; ov.z = sv.z * k; ov.w = sv.w * k;
    if (it < 2) {
      #pragma unroll
      for (int j = 0; j < 18; ++j) {
        float d = P[j].x * ov.x + P[j].y * ov.y + P[j].z * ov.z + P[j].w * ov.w;
        d = red32(red16(d));            // VALU permlane butterfly, no LDS
        c[j] += __expf(d);
      }
    } else if (fq == 0) {
      // out[n][o*16 + l][h][w0+pix], l = q*4 + reg (reps write identical values)
      float* op = out + ((n * 8 + o) * 16 + (q << 2)) * 1024 + h * 32 + w0 + pix;
      op[0]    = ov.x;
      op[1024] = ov.y;
      op[2048] = ov.z;
      op[3072] = ov.w;
    }
  }
}

extern "C" void kernel_launch(void* const* d_in, const int* in_sizes, int n_in,
                              void* d_out, int out_size, void* d_ws, size_t ws_size,
                              hipStream_t stream) {
  const float* x = (const float*)d_in[0];
  const float* w = (const float*)d_in[1];
  float* outp    = (float*)d_out;
  ushort* wT = (ushort*)d_ws;                   // 9216 * 32 B = 294912 B
  ushort* xT = (ushort*)((char*)d_ws + 294912); // 4096 * 256 B = 1048576 B
  prep<<<dim3(164), dim3(256), 0, stream>>>(x, w, wT, xT);
  caps_main<<<dim3(8192), dim3(256), 0, stream>>>(wT, xT, outp);  // 4x rep probe
}

// Round 12
// 75.533 us; speedup vs baseline: 1.4876x; 1.4876x over previous
//
#include <hip/hip_runtime.h>
#include <hip/hip_bf16.h>

// CapsuleConv2d fused, MFMA edition v11 = v6 + vectorized/packed routing + occ 4.
// N=4, C=64 (G=8 x IN_LEN=8), H=W=32, O=8, L=16, F=72 (G x 3x3), pad1 stride1.
//
// r11 PMC (4x probe): VALUBusy 81%, MfmaUtil 6%, VGPR_Count 60 -> caps_main is
// VALU-issue bound with P[18]f32x4 in AGPRs (accvgpr traffic ~doubles insts).
// v11: (1) routing math in f32x4/f32x2 vector form -> v_pk_fma_f32/v_pk_add_f32
// (2 FLOP/inst, VOP3P forces VGPR residency of P); (2) delta reduces pair-packed
// (one permlane pair + pk_add per stage for TWO f); (3) __launch_bounds__(256,4)
// -> 4 blocks/CU (v9-vs-v7 showed the 128 cap is safe), cutting dispatch rounds.
//
// prep: x fp32 -> xT per pixel [hi c0..63 | lo c0..63] (bf16 split, LDS transpose);
//       w fp32 -> wT records [hi p0..7 | lo p0..7].
// caps_main: block = (n,o,h,wtile16) = 2048; 4 waves = 4 f-quadrants (18 f).
//   Priors: one mfma_f32_16x16x32_bf16 per f; K-octets = exact bf16-split:
//     q0: w_hi*x_hi, q1: w_hi*x_lo, q2: w_lo*x_hi, q3: w_lo*x_lo.
//   D-layout: col=lane&15=pix, row=(lane>>4)*4+reg=l  [m89-verified].
//   sbuf slot swizzle: 2-way banks on the s-exchange.

typedef short bf16x8 __attribute__((ext_vector_type(8)));
typedef float f32x4 __attribute__((ext_vector_type(4)));
typedef float f32x2 __attribute__((ext_vector_type(2)));
typedef unsigned int uint2v __attribute__((ext_vector_type(2)));

__device__ __forceinline__ float red16(float v) {
#if __has_builtin(__builtin_amdgcn_permlane16_swap)
  uint2v r = __builtin_amdgcn_permlane16_swap(__float_as_uint(v), __float_as_uint(v),
                                              false, false);
  return __uint_as_float(r[0]) + __uint_as_float(r[1]);
#else
  return v + __shfl_xor(v, 16);
#endif
}

__device__ __forceinline__ float red32(float v) {
#if __has_builtin(__builtin_amdgcn_permlane32_swap)
  uint2v r = __builtin_amdgcn_permlane32_swap(__float_as_uint(v), __float_as_uint(v),
                                              false, false);
  return __uint_as_float(r[0]) + __uint_as_float(r[1]);
#else
  return v + __shfl_xor(v, 32);
#endif
}

// paired (2 x f32) cross-lane reduces: 2 permlane + 1 pk_add per stage
__device__ __forceinline__ f32x2 red16v2(f32x2 v) {
#if __has_builtin(__builtin_amdgcn_permlane16_swap)
  uint2v r0 = __builtin_amdgcn_permlane16_swap(__float_as_uint(v.x), __float_as_uint(v.x), false, false);
  uint2v r1 = __builtin_amdgcn_permlane16_swap(__float_as_uint(v.y), __float_as_uint(v.y), false, false);
  f32x2 a = {__uint_as_float(r0[0]), __uint_as_float(r1[0])};
  f32x2 b = {__uint_as_float(r0[1]), __uint_as_float(r1[1])};
  return a + b;
#else
  return (f32x2){v.x + __shfl_xor(v.x, 16), v.y + __shfl_xor(v.y, 16)};
#endif
}

__device__ __forceinline__ f32x2 red32v2(f32x2 v) {
#if __has_builtin(__builtin_amdgcn_permlane32_swap)
  uint2v r0 = __builtin_amdgcn_permlane32_swap(__float_as_uint(v.x), __float_as_uint(v.x), false, false);
  uint2v r1 = __builtin_amdgcn_permlane32_swap(__float_as_uint(v.y), __float_as_uint(v.y), false, false);
  f32x2 a = {__uint_as_float(r0[0]), __uint_as_float(r1[0])};
  f32x2 b = {__uint_as_float(r0[1]), __uint_as_float(r1[1])};
  return a + b;
#else
  return (f32x2){v.x + __shfl_xor(v.x, 32), v.y + __shfl_xor(v.y, 32)};
#endif
}

__device__ __forceinline__ uint pack_split(float v) {
  __hip_bfloat16 hb = __float2bfloat16(v);
  float hf = __bfloat162float(hb);
  __hip_bfloat16 lb = __float2bfloat16(v - hf);
  return (uint)(*(ushort*)&hb) | ((uint)(*(ushort*)&lb) << 16);
}

__global__ __launch_bounds__(256)
void prep(const float* __restrict__ x, const float* __restrict__ w,
          ushort* __restrict__ wT, ushort* __restrict__ xT) {
  const int b = blockIdx.x;
  if (b < 128) {
    // ---- x part: one h-row (32 pixels) per block ----
    __shared__ uint lds[32 * 65];  // [pix][c], hi|lo packed
    const int n = b >> 5, h0 = b & 31;
    const float* src = x + n * 65536 + h0 * 32;
    for (int i = threadIdx.x; i < 2048; i += 256) {
      const int c = i >> 5, p = i & 31;
      lds[p * 65 + c] = pack_split(src[c * 1024 + p]);
    }
    __syncthreads();
    uint* dst = (uint*)xT + (n * 1024 + h0 * 32) * 64;
    for (int i = threadIdx.x; i < 512; i += 256) {
      const int pix = i >> 4, seg = i & 15;        // seg 0..7 hi, 8..15 lo
      const uint* row = &lds[pix * 65 + (seg & 7) * 8];
      uint4 v;
      if (seg < 8) {
        v.x = (row[0] & 0xffffu) | (row[1] << 16);
        v.y = (row[2] & 0xffffu) | (row[3] << 16);
        v.z = (row[4] & 0xffffu) | (row[5] << 16);
        v.w = (row[6] & 0xffffu) | (row[7] << 16);
      } else {
        v.x = (row[0] >> 16) | (row[1] & 0xffff0000u);
        v.y = (row[2] >> 16) | (row[3] & 0xffff0000u);
        v.z = (row[4] >> 16) | (row[5] & 0xffff0000u);
        v.w = (row[6] >> 16) | (row[7] & 0xffff0000u);
      }
      *(uint4*)(dst + pix * 64 + seg * 4) = v;
    }
  } else {
    // ---- w part: t = record index (o*72+f)*16+l, 9216 total ----
    const int t = (b - 128) * 256 + threadIdx.x;
    if (t >= 9216) return;
    const float* src = w + t * 8;
    uint hi[4], lo[4];
    #pragma unroll
    for (int p2 = 0; p2 < 4; ++p2) {
      uint a = pack_split(src[p2 * 2]);
      uint c = pack_split(src[p2 * 2 + 1]);
      hi[p2] = (a & 0xffffu) | (c << 16);
      lo[p2] = (a >> 16) | (c & 0xffff0000u);
    }
    uint* dstp = (uint*)(wT + t * 16);
    *(uint4*)dstp       = make_uint4(hi[0], hi[1], hi[2], hi[3]);
    *(uint4*)(dstp + 4) = make_uint4(lo[0], lo[1], lo[2], lo[3]);
  }
}

__global__ __launch_bounds__(256, 4)
void caps_main(const ushort* __restrict__ wT, const ushort* __restrict__ xT,
               float* __restrict__ out) {
  const int b  = blockIdx.x;
  const int wt = b & 1, h = (b >> 1) & 31, o = (b >> 6) & 7, n = b >> 9;
  const int w0 = wt * 16;
  const int tid = threadIdx.x, lane = tid & 63, fq = tid >> 6;
  const int pix = lane & 15, q = lane >> 4;

  // x window: 3 rows x 18 cols, per col 64 uints ([hi 32 | lo 32]), stride 68
  __shared__ uint  xs[54 * 68];          // 14688 B
  __shared__ float sbuf[2][4 * 256];     // 8192 B, parity-buffered s exchange

  // ---- stage x window (uint4 copies; zero-fill pads) ----
  for (int i = tid; i < 54 * 16; i += 256) {
    const int r = i >> 4, seg = i & 15;
    const int kh = r / 18, c = r % 18;
    const int hh = h + kh - 1, ww = w0 + c - 1;
    uint4 v = make_uint4(0u, 0u, 0u, 0u);
    if ((unsigned)hh < 32u && (unsigned)ww < 32u) {
      const uint* g = (const uint*)xT + (n * 1024 + hh * 32 + ww) * 64 + seg * 4;
      v = *(const uint4*)g;
    }
    *(uint4*)&xs[r * 68 + seg * 4] = v;
  }
  __syncthreads();

  // ---- priors: 18 MFMAs, one per f = fq*18 + j; exact bf16-split ----
  f32x4 P[18];
  const f32x4 zacc = {0.f, 0.f, 0.f, 0.f};
  const ushort* wA = wT + ((o * 72 + fq * 18) * 16 + pix) * 16 + ((q >= 2) ? 8 : 0);
  const int xw_lane = pix * 68 + ((q & 1) ? 32 : 0);
  #pragma unroll
  for (int j = 0; j < 18; ++j) {
    const int g = fq * 2 + (j >= 9 ? 1 : 0);
    const int s = j % 9, kh = s / 3, kw = s % 3;
    const bf16x8 a  = *(const bf16x8*)(wA + j * 256);
    const bf16x8 bv = *(const bf16x8*)&xs[(kh * 18 + kw) * 68 + g * 4 + xw_lane];
    P[j] = __builtin_amdgcn_mfma_f32_16x16x32_bf16(a, bv, zacc, 0, 0, 0);
  }

  // ---- routing: lane owns (pix, l = q*4 + reg), 18 f x 4 l priors in regs ----
  float c[18];
  #pragma unroll
  for (int j = 0; j < 18; ++j) c[j] = 1.f;

  // swizzled slot: 16 consecutive lanes cover all 8 four-bank windows (2-way).
  const int sidx = pix * 16 + (((q + (pix >> 1)) & 3) << 2);
  #pragma unroll
  for (int it = 0; it < 3; ++it) {
    // s-partials: f32x4 vector fma -> v_pk_fma_f32 pairs
    f32x4 sp = {0.f, 0.f, 0.f, 0.f};
    #pragma unroll
    for (int j = 0; j < 18; ++j) sp += P[j] * c[j];
    float* sb = sbuf[it & 1];
    *(f32x4*)&sb[fq * 256 + sidx] = sp;
    __syncthreads();
    f32x4 sv = *(const f32x4*)&sb[sidx];
    #pragma unroll
    for (int k4 = 1; k4 < 4; ++k4) sv += *(const f32x4*)&sb[k4 * 256 + sidx];
    sv *= 0.125f;
    // squash: qq = sum_l s^2 via packed dot + lq-lane reduce
    f32x2 q2 = (f32x2){sv.x, sv.y} * (f32x2){sv.x, sv.y}
             + (f32x2){sv.z, sv.w} * (f32x2){sv.z, sv.w};
    float qq = red32(red16(q2.x + q2.y));
    const float k = sqrtf(qq) / (1.f + qq);
    f32x4 ov = sv * k;
    if (it < 2) {
      const f32x2 ovlo = {ov.x, ov.y}, ovhi = {ov.z, ov.w};
      #pragma unroll
      for (int jj = 0; jj < 9; ++jj) {
        const int j0 = 2 * jj, j1 = j0 + 1;
        // packed dots for the f-pair
        f32x2 t0 = (f32x2){P[j0].x, P[j0].y} * ovlo
                 + (f32x2){P[j0].z, P[j0].w} * ovhi;
        f32x2 t1 = (f32x2){P[j1].x, P[j1].y} * ovlo
                 + (f32x2){P[j1].z, P[j1].w} * ovhi;
        f32x2 dd = {t0.x + t0.y, t1.x + t1.y};
        dd = red32v2(red16v2(dd));      // paired VALU butterfly
        c[j0] += __expf(dd.x);
        c[j1] += __expf(dd.y);
      }
    } else if (fq == 0) {
      // out[n][o*16 + l][h][w0+pix], l = q*4 + reg
      float* op = out + ((n * 8 + o) * 16 + (q << 2)) * 1024 + h * 32 + w0 + pix;
      op[0]    = ov.x;
      op[1024] = ov.y;
      op[2048] = ov.z;
      op[3072] = ov.w;
    }
  }
}

extern "C" void kernel_launch(void* const* d_in, const int* in_sizes, int n_in,
                              void* d_out, int out_size, void* d_ws, size_t ws_size,
                              hipStream_t stream) {
  const float* x = (const float*)d_in[0];
  const float* w = (const float*)d_in[1];
  float* outp    = (float*)d_out;
  ushort* wT = (ushort*)d_ws;                   // 9216 * 32 B = 294912 B
  ushort* xT = (ushort*)((char*)d_ws + 294912); // 4096 * 256 B = 1048576 B
  prep<<<dim3(164), dim3(256), 0, stream>>>(x, w, wT, xT);
  caps_main<<<dim3(2048), dim3(256), 0, stream>>>(wT, xT, outp);
}